// Round 1
// baseline (549.892 us; speedup 1.0000x reference)
//
#include <hip/hip_runtime.h>

// Max pool 2x2, stride 2, pad 0 on NCHW fp32 (32,64,224,224) -> (32,64,112,112).
// Memory-bound: 411 MB read + 103 MB write, no input reuse -> pure streaming.
// Each thread: 4 output pixels (one float4 store), 4 float4 loads (2 per input row).

#define W_IN   224
#define H_IN   224
#define OW     112
#define OH     112
#define HW_IN  (W_IN * H_IN)
#define NPR    (OW / 4)          // 28 float4 outputs per output row

__global__ __launch_bounds__(256) void CustomMaxPool2D_48137993453716_kernel(
    const float* __restrict__ x, float* __restrict__ out, int total_f4) {
  const int stride = gridDim.x * blockDim.x;
  for (int t = blockIdx.x * blockDim.x + threadIdx.x; t < total_f4; t += stride) {
    // t -> (image-channel, output row, float4-within-row)
    int r  = t / NPR;            // row id across N*C*OH (magic-mul by compiler)
    int q  = t - r * NPR;        // float4 index within output row [0,28)
    int ic = r / OH;             // image-channel [0, 32*64)
    int oh = r - ic * OH;        // output row [0,112)

    const float4* row0 = reinterpret_cast<const float4*>(
        x + (size_t)ic * HW_IN + (size_t)(2 * oh) * W_IN);
    const float4* row1 = row0 + (W_IN / 4);

    float4 a0 = row0[2 * q];
    float4 a1 = row0[2 * q + 1];
    float4 b0 = row1[2 * q];
    float4 b1 = row1[2 * q + 1];

    float4 o;
    o.x = fmaxf(fmaxf(a0.x, a0.y), fmaxf(b0.x, b0.y));
    o.y = fmaxf(fmaxf(a0.z, a0.w), fmaxf(b0.z, b0.w));
    o.z = fmaxf(fmaxf(a1.x, a1.y), fmaxf(b1.x, b1.y));
    o.w = fmaxf(fmaxf(a1.z, a1.w), fmaxf(b1.z, b1.w));

    reinterpret_cast<float4*>(out)[t] = o;
  }
}

extern "C" void kernel_launch(void* const* d_in, const int* in_sizes, int n_in,
                              void* d_out, int out_size, void* d_ws, size_t ws_size,
                              hipStream_t stream) {
  const float* x = (const float*)d_in[0];
  float* out = (float*)d_out;

  // out_size = 32*64*112*112 = 25,690,112 elements; /4 per thread
  int total_f4 = out_size / 4;                 // 6,422,528
  int block = 256;
  int grid = (total_f4 + block - 1) / block;   // 25,088
  if (grid > 2048) grid = 2048;                // 256 CU x 8 blocks, grid-stride rest

  CustomMaxPool2D_48137993453716_kernel<<<grid, block, 0, stream>>>(x, out, total_f4);
}

// Round 2
// 528.505 us; speedup vs baseline: 1.0405x; 1.0405x over previous
//
#include <hip/hip_runtime.h>

// Max pool 2x2, stride 2, pad 0 on NCHW fp32 (32,64,224,224) -> (32,64,112,112).
// Pure streaming: 411 MB read + 103 MB write, zero input reuse.
// R2 changes vs R1: exact grid (no grid-stride loop, index math once/thread),
// nontemporal loads+stores (input > L3, no reuse -> don't pollute caches),
// 32-bit address arithmetic.

#define W_IN   224
#define OH     112
#define HW_IN  (224 * 224)
#define NPR    (112 / 4)         // 28 float4 outputs per output row

typedef float f32x4 __attribute__((ext_vector_type(4)));

__global__ __launch_bounds__(256) void CustomMaxPool2D_48137993453716_kernel(
    const float* __restrict__ x, float* __restrict__ out) {
  unsigned t = blockIdx.x * 256u + threadIdx.x;   // [0, 6422528) — grid exact

  // t -> (image-channel ic, output row oh, float4-within-row q)
  unsigned r  = t / NPR;          // compiler magic-mul
  unsigned q  = t - r * NPR;      // [0,28)
  unsigned ic = r / OH;           // [0, 32*64)
  unsigned oh = r - ic * OH;      // [0,112)

  const f32x4* row0 = reinterpret_cast<const f32x4*>(
      x + ic * (unsigned)HW_IN + (2u * oh) * (unsigned)W_IN);
  const f32x4* row1 = row0 + (W_IN / 4);

  f32x4 a0 = __builtin_nontemporal_load(&row0[2u * q]);
  f32x4 a1 = __builtin_nontemporal_load(&row0[2u * q + 1u]);
  f32x4 b0 = __builtin_nontemporal_load(&row1[2u * q]);
  f32x4 b1 = __builtin_nontemporal_load(&row1[2u * q + 1u]);

  f32x4 o;
  o.x = fmaxf(fmaxf(a0.x, a0.y), fmaxf(b0.x, b0.y));
  o.y = fmaxf(fmaxf(a0.z, a0.w), fmaxf(b0.z, b0.w));
  o.z = fmaxf(fmaxf(a1.x, a1.y), fmaxf(b1.x, b1.y));
  o.w = fmaxf(fmaxf(a1.z, a1.w), fmaxf(b1.z, b1.w));

  __builtin_nontemporal_store(o, &reinterpret_cast<f32x4*>(out)[t]);
}

extern "C" void kernel_launch(void* const* d_in, const int* in_sizes, int n_in,
                              void* d_out, int out_size, void* d_ws, size_t ws_size,
                              hipStream_t stream) {
  const float* x = (const float*)d_in[0];
  float* out = (float*)d_out;

  // out_size = 32*64*112*112 = 25,690,112 elements; 4 per thread -> 6,422,528
  // threads; 256/block -> 25,088 blocks, EXACT (no tail).
  int total_f4 = out_size / 4;
  int block = 256;
  int grid = (total_f4 + block - 1) / block;

  CustomMaxPool2D_48137993453716_kernel<<<grid, block, 0, stream>>>(x, out);
}